// Round 12
// baseline (161.596 us; speedup 1.0000x reference)
//
#include <hip/hip_runtime.h>
#include <hip/hip_bf16.h>

typedef __attribute__((ext_vector_type(8))) short short8;
typedef __attribute__((ext_vector_type(4))) float f32x4;

#define NT 65536

__device__ __forceinline__ unsigned short f2bf(float f) {
    union { float f; unsigned int u; } v; v.f = f;
    unsigned int u = v.u;
    unsigned int r = (u + 0x7fffu + ((u >> 16) & 1u)) >> 16;  // RNE
    return (unsigned short)r;
}

__device__ __forceinline__ unsigned int cvt_pk_bf16(float lo, float hi) {
    unsigned int r;
    asm("v_cvt_pk_bf16_f32 %0, %1, %2" : "=v"(r) : "v"(lo), "v"(hi));
    return r;
}

#define LGKM0()  asm volatile("s_waitcnt lgkmcnt(0)" ::: "memory")
#define BAR()    __builtin_amdgcn_s_barrier()
#define SB0()    __builtin_amdgcn_sched_barrier(0)

// ---------------- prep (all 3 sources): bf16 B panel + per-k params ----------------
// Panel row n: k16=n>>5, typ=(n>>4)&1, r=n&15 -> k=k16*16+r; typ0=w, typ1=beta.
// prm per source (5*256 f32): [0:256)=||w_k||^2, [256)=gam^2, [512)=eta^2, [768)=alpha, [1024)=sig^2
__global__ void prep_kernel(const float* __restrict__ w0, const float* __restrict__ b0,
                            const float* __restrict__ a0, const float* __restrict__ s0,
                            const float* __restrict__ e0, const float* __restrict__ g0,
                            const float* __restrict__ w1, const float* __restrict__ b1,
                            const float* __restrict__ a1, const float* __restrict__ s1,
                            const float* __restrict__ e1, const float* __restrict__ g1,
                            const float* __restrict__ w2, const float* __restrict__ b2,
                            const float* __restrict__ a2, const float* __restrict__ s2,
                            const float* __restrict__ e2, const float* __restrict__ g2,
                            unsigned short* __restrict__ bc, float* __restrict__ prmAll) {
    __shared__ float red[2];
    const int bx = blockIdx.x;
    const int s = bx >> 9;            // 0..2
    const int n = bx & 511;           // panel row
    const int P = 512 >> s;
    const float* w   = (s == 0) ? w0 : ((s == 1) ? w1 : w2);
    const float* bet = (s == 0) ? b0 : ((s == 1) ? b1 : b2);
    const float* alp = (s == 0) ? a0 : ((s == 1) ? a1 : a2);
    const float* sig = (s == 0) ? s0 : ((s == 1) ? s1 : s2);
    const float* eta = (s == 0) ? e0 : ((s == 1) ? e1 : e2);
    const float* gam = (s == 0) ? g0 : ((s == 1) ? g1 : g2);
    unsigned short* dstb = bc + ((s == 0) ? 0 : ((s == 1) ? (512 * 512) : (512 * 512 + 512 * 256)));
    float* prm = prmAll + 1280 * s;

    const int tid = threadIdx.x;      // 128
    const int k16 = n >> 5;
    const int typ = (n >> 4) & 1;
    const int k = k16 * 16 + (n & 15);
    const bool isw = (typ == 0);
    const float* src = (isw ? w : bet) + (size_t)k * P;
    unsigned short* dst = dstb + (size_t)n * P;
    float ss = 0.f;
    for (int c = tid; c < P; c += 128) {
        float f = src[c];
        dst[c] = f2bf(f);
        if (isw) ss += f * f;
    }
#pragma unroll
    for (int m = 1; m < 64; m <<= 1) ss += __shfl_xor(ss, m);
    if ((tid & 63) == 0) red[tid >> 6] = ss;
    __syncthreads();
    if (isw && tid == 0) prm[k] = red[0] + red[1];
    if (n == 0) {
        for (int kk = tid; kk < 256; kk += 128) {
            float g = gam[kk], e = eta[kk];
            prm[256 + kk]  = g * g;
            prm[512 + kk]  = e * e;
            prm[768 + kk]  = alp[kk];
            prm[1024 + kk] = sig[kk] * sig[kk];
        }
    }
}

// ---------------- fused (all sources): 256x256-tile GEMM + RBF epilogue ----------------
// See round journal. 8 waves (2wr x 4wc), per-wave 128x64 sub-tile (acc[8][4] frags).
// BK=32 K-tiles, 3-deep LDS buffers, reg-staged A(panel bf16) + X(x fp32->bf16),
// issue distance 2 tiles, ONE barrier + lgkmcnt(0) per tile, NO vmcnt (reg-dep waits).
// LDS rows padded to 80B (5x16B slots, stride 5 mod 8) -> conflict-free reads/writes, no swizzle.
// Swapped MFMA mfma(panel, x): k lane-local -> epilogue = register math + 2 shuffles.
template<int P>
__device__ __forceinline__ void body(const float* __restrict__ x,
                                     const unsigned short* __restrict__ Bc,
                                     const float* __restrict__ prm,
                                     float* __restrict__ pwsS, int h, int mt,
                                     unsigned short (*As)[256 * 40], unsigned short (*Xs)[256 * 40],
                                     float* xn2, float (*part)[256][3], int tid) {
    constexpr int NK = P / 32;
    const int lane = tid & 63, wv = tid >> 6;
    const int wr = wv >> 2, wc = wv & 3;
    const int l15 = lane & 15, l4 = lane >> 4;
    const int row0 = mt * 256;

    // staging map: thread -> row = tid>>1 (0..255), 16-col half = tid&1
    const int rx = tid >> 1, hx = tid & 1;
    const float* xp = x + (size_t)(row0 + rx) * P + hx * 16;
    const unsigned short* ap = Bc + (size_t)(256 * h + rx) * P + hx * 16;

    f32x4 acc[8][4];
#pragma unroll
    for (int m = 0; m < 8; m++)
#pragma unroll
        for (int nf = 0; nf < 4; nf++) acc[m][nf] = (f32x4){0.f, 0.f, 0.f, 0.f};

    float4 xr[3][4];
    uint4  ar[3][2];
    float ssx = 0.f;
    short8 Bfr[4];

    auto issue = [&](int set, int t) {
#pragma unroll
        for (int j = 0; j < 4; j++) xr[set][j] = *(const float4*)(xp + t * 32 + j * 4);
#pragma unroll
        for (int q = 0; q < 2; q++) ar[set][q] = *(const uint4*)(ap + t * 32 + q * 8);
    };
    auto stage = [&](int set, int buf) {
#pragma unroll
        for (int q = 0; q < 2; q++) {
            float4 a = xr[set][2 * q], b = xr[set][2 * q + 1];
            ssx += a.x*a.x + a.y*a.y + a.z*a.z + a.w*a.w
                 + b.x*b.x + b.y*b.y + b.z*b.z + b.w*b.w;
            uint4 pk = { cvt_pk_bf16(a.x, a.y), cvt_pk_bf16(a.z, a.w),
                         cvt_pk_bf16(b.x, b.y), cvt_pk_bf16(b.z, b.w) };
            *(uint4*)(&Xs[buf][rx * 40 + (hx * 2 + q) * 8]) = pk;
        }
#pragma unroll
        for (int q = 0; q < 2; q++)
            *(uint4*)(&As[buf][rx * 40 + (hx * 2 + q) * 8]) = ar[set][q];
    };
    auto compute = [&](int buf) {
#pragma unroll
        for (int mh = 0; mh < 2; mh++) {
            short8 Af[4];
            if (mh == 0) {
#pragma unroll
                for (int nf = 0; nf < 4; nf++)
                    Bfr[nf] = *(const short8*)(&Xs[buf][(wc * 64 + nf * 16 + l15) * 40 + l4 * 8]);
            }
#pragma unroll
            for (int i = 0; i < 4; i++)
                Af[i] = *(const short8*)(&As[buf][(wr * 128 + (mh * 4 + i) * 16 + l15) * 40 + l4 * 8]);
            SB0();
            __builtin_amdgcn_s_setprio(1);
#pragma unroll
            for (int i = 0; i < 4; i++)
#pragma unroll
                for (int nf = 0; nf < 4; nf++)
                    acc[mh * 4 + i][nf] = __builtin_amdgcn_mfma_f32_16x16x32_bf16(
                        Af[i], Bfr[nf], acc[mh * 4 + i][nf], 0, 0, 0);
            __builtin_amdgcn_s_setprio(0);
            SB0();
        }
    };

    // ---- prologue ----
    issue(0, 0); SB0();
    issue(1, 1); SB0();
    stage(0, 0);
    issue(2, 2); SB0();
    LGKM0(); BAR(); SB0();

    // ---- main loop: 1 barrier per K-tile ----
#pragma unroll
    for (int t = 0; t < NK; t++) {
        if (t + 1 < NK) { stage((t + 1) % 3, (t + 1) % 3); SB0(); }
        if (t + 3 < NK) { issue((t + 3) % 3, t + 3); SB0(); }
        compute(t % 3);
        LGKM0(); SB0(); BAR(); SB0();
    }

    // ---- ||x||^2 (exact, from fp32 staging) ----
    ssx += __shfl_xor(ssx, 1);
    if (hx == 0) xn2[rx] = ssx;
    __syncthreads();

    // ---- epilogue: lane holds panel-row = wr*128 + m*16 + 4*l4 + j, x-col = wc*64+nf*16+l15
    // m = 2g+typ: g -> k16 = h*8 + wr*4 + g, k = k16*16 + 4*l4 + j (lane-local)
    f32x4 wn2[4], g2[4], hv[4], alv[4], s2v[4];
#pragma unroll
    for (int g = 0; g < 4; g++) {
        const int kb = (h * 8 + wr * 4 + g) * 16 + 4 * l4;
        wn2[g] = *(const f32x4*)(prm + kb);
        g2[g]  = *(const f32x4*)(prm + 256 + kb);
        hv[g]  = *(const f32x4*)(prm + 512 + kb);
        alv[g] = *(const f32x4*)(prm + 768 + kb);
        s2v[g] = *(const f32x4*)(prm + 1024 + kb);
    }
#pragma unroll
    for (int nf = 0; nf < 4; nf++) {
        const int col = wc * 64 + nf * 16 + l15;
        const float xv = xn2[col];
        float hs = 0.f, ms = 0.f, gs = 0.f;
#pragma unroll
        for (int g = 0; g < 4; g++) {
#pragma unroll
            for (int j = 0; j < 4; j++) {
                const float aw = acc[2 * g][nf][j];
                const float ab = acc[2 * g + 1][nf][j];
                const float d2 = xv - 2.f * aw + wn2[g][j];
                const float e  = __expf(-g2[g][j] * d2);
                const float ah = e * hv[g][j];
                hs += ah;
                ms += (ab + alv[g][j]) * ah;
                gs += s2v[g][j] * ah * ah;
            }
        }
        hs += __shfl_xor(hs, 16); hs += __shfl_xor(hs, 32);
        ms += __shfl_xor(ms, 16); ms += __shfl_xor(ms, 32);
        gs += __shfl_xor(gs, 16); gs += __shfl_xor(gs, 32);
        if (l4 == 0) {
            part[wr][col][0] = hs;
            part[wr][col][1] = ms;
            part[wr][col][2] = gs;
        }
    }
    __syncthreads();
    if (tid < 256) {
#pragma unroll
        for (int v = 0; v < 3; v++)
            pwsS[(size_t)(h * 3 + v) * NT + row0 + tid] = part[0][tid][v] + part[1][tid][v];
    }
}

__global__ __launch_bounds__(512, 2)
void fused_all(const float* __restrict__ x0, const float* __restrict__ x1, const float* __restrict__ x2,
               const unsigned short* __restrict__ bcAll, const float* __restrict__ prmAll,
               float* __restrict__ pws) {
    __shared__ unsigned short As[3][256 * 40];   // 60 KB (panel, padded 80B rows)
    __shared__ unsigned short Xs[3][256 * 40];   // 60 KB (x bf16)
    __shared__ float xn2[256];
    __shared__ float part[2][256][3];

    const int bx = blockIdx.x;
    const int src = bx >> 9;
    const int local = bx & 511;
    const int h = local >> 8;
    const int mt = local & 255;
    const int tid = threadIdx.x;

    if (src == 0)
        body<512>(x0, bcAll, prmAll, pws, h, mt, As, Xs, xn2, part, tid);
    else if (src == 1)
        body<256>(x1, bcAll + 512 * 512, prmAll + 1280, pws + (size_t)6 * NT, h, mt, As, Xs, xn2, part, tid);
    else
        body<128>(x2, bcAll + 512 * 512 + 512 * 256, prmAll + 2560, pws + (size_t)12 * NT, h, mt, As, Xs, xn2, part, tid);
}

// ---------------- combine: all outputs from 2 h-partials per source ----------------
__global__ void combine_kernel(const float* __restrict__ pws,
                               const float* __restrict__ d0, const float* __restrict__ d1,
                               const float* __restrict__ d2, float* __restrict__ out) {
    const int t = blockIdx.x * 256 + threadIdx.x;
    float mux[3], s2x[3], hx[3];
#pragma unroll
    for (int s = 0; s < 3; s++) {
        const float* bb = pws + (size_t)s * 6 * NT;
        const float hh = bb[t] + bb[(size_t)3 * NT + t];
        const float mm = bb[(size_t)1 * NT + t] + bb[(size_t)4 * NT + t];
        const float gg = bb[(size_t)2 * NT + t] + bb[(size_t)5 * NT + t];
        mux[s] = mm / hh; s2x[s] = gg / (hh * hh); hx[s] = hh;
        out[(size_t)s * NT + t]       = mux[s];
        out[(size_t)(4 + s) * NT + t] = s2x[s];
        out[(size_t)(8 + s) * NT + t] = hh;
    }
    const float sd0 = 1.f / (1.f + __expf(-d0[0]));
    const float sd1 = 1.f / (1.f + __expf(-d1[0]));
    const float sd2 = 1.f / (1.f + __expf(-d2[0]));
    const float c0 = hx[0] * sd0, c1 = hx[1] * sd1, c2 = hx[2] * sd2;
    const float den = c0 + c1 + c2;
    const float muc = mux[0] * c0 + mux[1] * c1 + mux[2] * c2;
    const float sgc = s2x[0] * c0 * c0 + s2x[1] * c1 * c1 + s2x[2] * c2 * c2;
    out[(size_t)3 * NT + t]  = muc / den;
    out[(size_t)7 * NT + t]  = sgc / (den * den);
    out[(size_t)11 * NT + t] = den;
}

extern "C" void kernel_launch(void* const* d_in, const int* in_sizes, int n_in,
                              void* d_out, int out_size, void* d_ws, size_t ws_size,
                              hipStream_t stream) {
    // input order per source i: x=8i, alpha=8i+1, beta=8i+2, sig=8i+3, eta=8i+4, gam=8i+5, w=8i+6, disc=8i+7
    const float* x0 = (const float*)d_in[0];
    const float* x1 = (const float*)d_in[8];
    const float* x2 = (const float*)d_in[16];

    unsigned short* bc = (unsigned short*)d_ws;                  // 512*(512+256+128) ushorts = 917504 B
    float* prmAll = (float*)((char*)d_ws + 917504);              // 3*1280 floats = 15360 B
    float* pws    = (float*)((char*)d_ws + 917504 + 15360);      // 18*NT floats = 4.72 MB
    float* out = (float*)d_out;

    prep_kernel<<<1536, 128, 0, stream>>>(
        (const float*)d_in[6],  (const float*)d_in[2],  (const float*)d_in[1],
        (const float*)d_in[3],  (const float*)d_in[4],  (const float*)d_in[5],
        (const float*)d_in[14], (const float*)d_in[10], (const float*)d_in[9],
        (const float*)d_in[11], (const float*)d_in[12], (const float*)d_in[13],
        (const float*)d_in[22], (const float*)d_in[18], (const float*)d_in[17],
        (const float*)d_in[19], (const float*)d_in[20], (const float*)d_in[21],
        bc, prmAll);

    fused_all<<<1536, 512, 0, stream>>>(x0, x1, x2, bc, prmAll, pws);
    combine_kernel<<<256, 256, 0, stream>>>(pws, (const float*)d_in[7], (const float*)d_in[15],
                                            (const float*)d_in[23], out);
}